// Round 16
// baseline (153.323 us; speedup 1.0000x reference)
//
#include <hip/hip_runtime.h>
#include <hip/hip_bf16.h>

#define BB 8
#define CIN 512
#define COUT 512
#define HH 64
#define WW 64

#define AFF_SCALE 0.044194173824159216f     // 1/sqrt(512)
#define CONV_SCALE 0.014731391274719736f    // 1/sqrt(4608)
#define CONV_SCALE2 (1.0f/4608.0f)

typedef short s16x8 __attribute__((ext_vector_type(8)));
typedef float f32x16 __attribute__((ext_vector_type(16)));

__device__ __forceinline__ unsigned short f2bf(float f) {
  __hip_bfloat16 h = __float2bfloat16(f);
  return *reinterpret_cast<unsigned short*>(&h);
}

// zero-register global->LDS DMA, 16B per lane; LDS dest = uniform base + lane*16
__device__ __forceinline__ void gload_lds16(const void* g, void* l) {
  __builtin_amdgcn_global_load_lds(
      (const __attribute__((address_space(1))) unsigned int*)g,
      (__attribute__((address_space(3))) unsigned int*)l, 16, 0, 0);
}

// ---------------------------------------------------------------------------
// prep1: fused {affine | wsq | wpack}  (independent passes, block-ranged)
// ---------------------------------------------------------------------------
__global__ __launch_bounds__(256) void prep1_kernel(
    const float* __restrict__ style, const float* __restrict__ wa,
    const float* __restrict__ ba, float* __restrict__ smod,
    const float* __restrict__ wc, float* __restrict__ wsq,
    ushort* __restrict__ wfrag) {
  int bb = blockIdx.x;
  if (bb < 1024) {
    int wid  = (bb << 2) + (threadIdx.x >> 6);
    int lane = threadIdx.x & 63;
    int b  = wid >> 9;
    int ic = wid & 511;
    const float* s = style + b * CIN;
    const float* w = wa + (size_t)ic * CIN;
    float sum = 0.f;
#pragma unroll
    for (int k = 0; k < CIN / 64; ++k) sum += s[lane + 64 * k] * w[lane + 64 * k];
#pragma unroll
    for (int off = 32; off; off >>= 1) sum += __shfl_down(sum, off, 64);
    if (lane == 0) smod[wid] = sum * AFF_SCALE + ba[ic];
  } else if (bb < 2048) {
    int i = (bb - 1024) * 256 + threadIdx.x;
    const float* p = wc + (size_t)i * 9;
    float s = 0.f;
#pragma unroll
    for (int k = 0; k < 9; ++k) { float v = p[k]; s += v * v; }
    wsq[i] = s;
  } else {
    int n = (bb - 2048) * 256 + threadIdx.x;   // < 294,912 = 144*16*2*64
    int l    = n & 63;
    int ks   = (n >> 6) & 1;
    int mf   = (n >> 7) & 15;
    int widx = n >> 11;           // 0..143
    int g = widx / 9, p = widx % 9;
    int kh = p % 3, kw = p / 3;   // position-order storage
    int oc  = mf * 32 + (l & 31);
    int ic0 = g * 32 + ks * 16 + 8 * (l >> 5);
    s16x8 o;
#pragma unroll
    for (int j = 0; j < 8; ++j) {
      float v = wc[((size_t)oc * CIN + ic0 + j) * 9 + kh * 3 + kw];
      o[j] = (short)f2bf(v);
    }
    *(s16x8*)(wfrag + (size_t)n * 8) = o;
  }
}

// ---------------------------------------------------------------------------
// prep2: fused {demod | premod}
// ---------------------------------------------------------------------------
__global__ __launch_bounds__(256) void prep2_kernel(
    const float* __restrict__ smod, const float* __restrict__ wsq,
    float* __restrict__ demod,
    const float* __restrict__ xin, ushort* __restrict__ xt) {
  int bb = blockIdx.x;
  if (bb < 1024) {
    int wid  = (bb << 2) + (threadIdx.x >> 6);
    int lane = threadIdx.x & 63;
    int b  = wid >> 9;
    int oc = wid & 511;
    const float* s = smod + b * CIN;
    const float* w = wsq + (size_t)oc * CIN;
    float sum = 0.f;
#pragma unroll
    for (int k = 0; k < CIN / 64; ++k) {
      float sv = s[lane + 64 * k];
      sum += sv * sv * w[lane + 64 * k];
    }
#pragma unroll
    for (int off = 32; off; off >>= 1) sum += __shfl_down(sum, off, 64);
    if (lane == 0) demod[wid] = rsqrtf(sum * CONV_SCALE2 + 1e-8f) * CONV_SCALE;
  } else {
    int n = (bb - 1024) * 256 + threadIdx.x;   // < 2,097,152
    int kg = n & 3;
    int x  = (n >> 2) & 63;
    int y  = (n >> 8) & 63;
    int g  = (n >> 14) & 15;
    int b  = n >> 18;
    int ic0 = g * 32 + kg * 8;
    const float* sp = smod + b * CIN + ic0;
    const float* xp = xin + (((size_t)b * CIN + ic0) * HH + y) * WW + x;
    s16x8 o;
#pragma unroll
    for (int j = 0; j < 8; ++j) {
      float v = xp[(size_t)j * HH * WW] * sp[j];
      o[j] = (short)f2bf(v);
    }
    *(s16x8*)(xt + (size_t)n * 8) = o;
  }
}

// ---------------------------------------------------------------------------
// conv_mfma (R16): pre-barrier A-fragment prefetch (the last serial latency).
// Block = 512 thr (8 waves: 4 wm x 2 wr), 256oc x 4rows, grid 256 = 1/CU.
// ws: 4 rotating 16KB buffers, stage-ahead 3 (WSISSUE(P) -> kstep P+3,
// buffer (GG+P+3)%4). Entry vmcnt(2) publishes ws[k] AND ws[k+1] ->
// AREAD for kstep k+1 issues at the END of kstep k (wA regs reused after
// their last MFMA), drains at the pre-barrier lgkmcnt(0). 8 of 9 positions
// start MFMAs post-barrier with zero load dependency.
// xs staging: 24 x 1KB chunks spread over ALL 8 waves (3 DMAs each) ->
// vmcnt ledger UNIFORM across waves: p0-p6 = 2, p7/p8 = 5 (stage3 bump).
// Out-of-range rows -> trash row (R14 fix). Last body peeled (R15 fix):
// no stage3, keeps WSISSUE(6) (publication window for p7's prefetch),
// drops WSISSUE(7)/(8) and the final AREAD.
// ---------------------------------------------------------------------------
#define XS_ROW 4224                 // 66 cols * 4 kg * 16 B
#define XS_BUF (6 * XS_ROW)         // 25344 B per buffer
#define WS_BUFSZ 16384              // one kstep of block weights (256oc x 32ic)

#define MFMA1(A_, B_, C_) __builtin_amdgcn_mfma_f32_32x32x16_bf16(A_, B_, C_, 0, 0, 0)

// one k-half (8 MFMAs)
#define MHK(KF, SX, SY) \
  __builtin_amdgcn_s_setprio(1); \
  acc[0][0] = MFMA1(wA[KF],     SX[0 + (KF)], acc[0][0]); \
  acc[1][0] = MFMA1(wA[2 + KF], SX[0 + (KF)], acc[1][0]); \
  acc[0][1] = MFMA1(wA[KF],     SX[2 + (KF)], acc[0][1]); \
  acc[1][1] = MFMA1(wA[2 + KF], SX[2 + (KF)], acc[1][1]); \
  acc[0][2] = MFMA1(wA[KF],     SY[0 + (KF)], acc[0][2]); \
  acc[1][2] = MFMA1(wA[2 + KF], SY[0 + (KF)], acc[1][2]); \
  acc[0][3] = MFMA1(wA[KF],     SY[2 + (KF)], acc[0][3]); \
  acc[1][3] = MFMA1(wA[2 + KF], SY[2 + (KF)], acc[1][3]); \
  __builtin_amdgcn_s_setprio(0);

// B-slot load: xs row (wr2 + RR) at x-shift DXI; frags [ph*2+ks]
#define LOADSLOT(S, RR, DXI) \
  S[0] = *(const s16x8*)(xs_r + (wr2 + (RR)) * XS_ROW + addrV[0][DXI][0]); \
  S[1] = *(const s16x8*)(xs_r + (wr2 + (RR)) * XS_ROW + addrV[0][DXI][1]); \
  S[2] = *(const s16x8*)(xs_r + (wr2 + (RR)) * XS_ROW + addrV[1][DXI][0]); \
  S[3] = *(const s16x8*)(xs_r + (wr2 + (RR)) * XS_ROW + addrV[1][DXI][1]);

// entry barriers: counted vmcnt, uniform across all waves
#define ENTRYB2 \
  __builtin_amdgcn_sched_barrier(0); \
  asm volatile("s_waitcnt vmcnt(2) lgkmcnt(0)" ::: "memory"); \
  __builtin_amdgcn_sched_barrier(0); \
  __builtin_amdgcn_s_barrier(); \
  __builtin_amdgcn_sched_barrier(0);

#define ENTRYB5 \
  __builtin_amdgcn_sched_barrier(0); \
  asm volatile("s_waitcnt vmcnt(5) lgkmcnt(0)" ::: "memory"); \
  __builtin_amdgcn_sched_barrier(0); \
  __builtin_amdgcn_s_barrier(); \
  __builtin_amdgcn_sched_barrier(0);

// A-fragment read from ws buffer BUF (compile-time)
#define AREADB(BUF) { \
  const char* wsp_ = wsL + (BUF) * WS_BUFSZ + aoff; \
  wA[0] = *(const s16x8*)(wsp_); \
  wA[1] = *(const s16x8*)(wsp_ + 1024); \
  wA[2] = *(const s16x8*)(wsp_ + 2048); \
  wA[3] = *(const s16x8*)(wsp_ + 3072); }

// issue ws DMA for kstep (g*9 + P + 3) into buffer (GG+P+3)%4
#define WSISSUE(GG, P) { \
  const char* s_ = wsg + (size_t)((P) + 3) * 32768; \
  char* d_ = wsdst + (((GG) + (P) + 3) & 3) * WS_BUFSZ; \
  gload_lds16(s_, d_); \
  gload_lds16(s_ + 8192, d_ + 8192); }

// xs staging: 3 chunks per wave (24 total), always 3 DMAs (trash for OOR)
__device__ __forceinline__ void stage3(const char* xtb, size_t gbase,
                                       const int* sdesc, char* xs_w,
                                       char* trash, int y0) {
  __builtin_amdgcn_sched_barrier(0);
#pragma unroll
  for (int j = 0; j < 3; ++j) {
    int d = sdesc[j];
    int so   = d & 8191;
    int doff = (d >> 13) & 32767;
    int r    = d >> 28;
    int gy = y0 - 1 + r;
    bool ok = (gy >= 0) && (gy < HH);
    int gyc = ok ? gy : (gy < 0 ? 0 : HH - 1);
    char* dst = ok ? (xs_w + doff) : trash;
    gload_lds16(xtb + gbase + (size_t)gyc * 4096 + so, dst);
  }
  __builtin_amdgcn_sched_barrier(0);
}

// normal body; GG = g%4 (compile-time). Positions p0..p8.
#define GBODY(GG) \
{ \
  const char* xs_r = (const char*)lds + ((GG) & 1) * XS_BUF; \
  char* xs_w = lds + ((((GG) & 1)) ^ 1) * XS_BUF; \
  const char* wsg = wssrc0 + (size_t)((g4 * 4 + (GG)) * 9) * 32768; \
  /*p0*/ ENTRYB2 \
         LOADSLOT(bA, 0, 0) LOADSLOT(bB, 1, 0) \
         WSISSUE(GG, 0) \
         MHK(0, bA, bB) LOADSLOT(bC, 2, 0) MHK(1, bA, bB) AREADB(((GG) + 1) & 3) \
  /*p1*/ ENTRYB2 WSISSUE(GG, 1) \
         MHK(0, bB, bC) LOADSLOT(bA, 3, 0) MHK(1, bB, bC) AREADB(((GG) + 2) & 3) \
  /*p2*/ ENTRYB2 WSISSUE(GG, 2) \
         MHK(0, bC, bA) LOADSLOT(bB, 0, 1) MHK(1, bC, bA) LOADSLOT(bC, 1, 1) AREADB(((GG) + 3) & 3) \
  /*p3*/ ENTRYB2 WSISSUE(GG, 3) \
         MHK(0, bB, bC) LOADSLOT(bA, 2, 1) MHK(1, bB, bC) AREADB(((GG) + 0) & 3) \
  /*p4*/ ENTRYB2 WSISSUE(GG, 4) \
         MHK(0, bC, bA) LOADSLOT(bB, 3, 1) MHK(1, bC, bA) AREADB(((GG) + 1) & 3) \
  /*p5*/ ENTRYB2 WSISSUE(GG, 5) \
         MHK(0, bA, bB) LOADSLOT(bC, 0, 2) MHK(1, bA, bB) LOADSLOT(bA, 1, 2) AREADB(((GG) + 2) & 3) \
  /*p6*/ ENTRYB2 WSISSUE(GG, 6) \
         stage3(xtb, (size_t)(b * 16 + g4 * 4 + (GG) + 1) * 262144, sdesc, xs_w, trash, y0); \
         MHK(0, bC, bA) LOADSLOT(bB, 2, 2) MHK(1, bC, bA) AREADB(((GG) + 3) & 3) \
  /*p7*/ ENTRYB5 WSISSUE(GG, 7) \
         MHK(0, bA, bB) LOADSLOT(bC, 3, 2) MHK(1, bA, bB) AREADB(((GG) + 0) & 3) \
  /*p8*/ ENTRYB5 WSISSUE(GG, 8) \
         MHK(0, bB, bC) MHK(1, bB, bC) AREADB(((GG) + 1) & 3) \
}

// peeled last body (g = 15, GG = 3): no stage3; keeps WSISSUE(6) (past-end
// read, valid memory) so p7's prefetch publication window holds; drops
// WSISSUE(7)/(8); p7/p8 entry = vmcnt(2) (exact: no stage3 ops in queue);
// no AREAD after p8.
#define GBODY_LAST \
{ \
  const char* xs_r = (const char*)lds + XS_BUF; \
  const char* wsg = wssrc0 + (size_t)(15 * 9) * 32768; \
  /*p0*/ ENTRYB2 \
         LOADSLOT(bA, 0, 0) LOADSLOT(bB, 1, 0) \
         WSISSUE(3, 0) \
         MHK(0, bA, bB) LOADSLOT(bC, 2, 0) MHK(1, bA, bB) AREADB(0) \
  /*p1*/ ENTRYB2 WSISSUE(3, 1) \
         MHK(0, bB, bC) LOADSLOT(bA, 3, 0) MHK(1, bB, bC) AREADB(1) \
  /*p2*/ ENTRYB2 WSISSUE(3, 2) \
         MHK(0, bC, bA) LOADSLOT(bB, 0, 1) MHK(1, bC, bA) LOADSLOT(bC, 1, 1) AREADB(2) \
  /*p3*/ ENTRYB2 WSISSUE(3, 3) \
         MHK(0, bB, bC) LOADSLOT(bA, 2, 1) MHK(1, bB, bC) AREADB(3) \
  /*p4*/ ENTRYB2 WSISSUE(3, 4) \
         MHK(0, bC, bA) LOADSLOT(bB, 3, 1) MHK(1, bC, bA) AREADB(0) \
  /*p5*/ ENTRYB2 WSISSUE(3, 5) \
         MHK(0, bA, bB) LOADSLOT(bC, 0, 2) MHK(1, bA, bB) LOADSLOT(bA, 1, 2) AREADB(1) \
  /*p6*/ ENTRYB2 WSISSUE(3, 6) \
         MHK(0, bC, bA) LOADSLOT(bB, 2, 2) MHK(1, bC, bA) AREADB(2) \
  /*p7*/ ENTRYB2 \
         MHK(0, bA, bB) LOADSLOT(bC, 3, 2) MHK(1, bA, bB) AREADB(3) \
  /*p8*/ ENTRYB2 \
         MHK(0, bB, bC) MHK(1, bB, bC) \
}

__global__ __launch_bounds__(512, 2) void conv_mfma(
    const ushort* __restrict__ xt,     // [8][16][64][64][32] bf16
    const ushort* __restrict__ wfrag,  // [144][16][2][64][8] bf16
    const float* __restrict__ demod,
    float* __restrict__ out) {
  // 2 xs + 4 ws + trash = 50688 + 65536 + 4224 = 120448 B -> 1 block/CU
  __shared__ char lds[2 * XS_BUF + 4 * WS_BUFSZ + XS_ROW];

  int tid = threadIdx.x;
  int l = tid & 63, w = tid >> 6;     // 8 waves
  int wm = w >> 1, wr = w & 1;        // oc-quarter (64oc), row-pair
  int wr2 = wr * 2;
  int bid = blockIdx.x;
  int ocb = bid & 1;                  // 2 oc-halves of 512
  int b   = (bid >> 1) & 7;
  int yt  = bid >> 4;                 // 0..15
  int y0  = yt * 4;

  const char* wsL = (const char*)lds + 2 * XS_BUF;
  char* wsdst = lds + 2 * XS_BUF + tid * 16;
  char* trash = lds + 2 * XS_BUF + 4 * WS_BUFSZ;

  f32x16 acc[2][4];
#pragma unroll
  for (int i = 0; i < 2; ++i)
#pragma unroll
    for (int j = 0; j < 4; ++j)
#pragma unroll
      for (int e = 0; e < 16; ++e) acc[i][j][e] = 0.f;

  // zero always-zero halo COLUMNS (col 0 -> chunks 0..3, col 65 -> 260..263)
  if (tid < 96) {
    int buf = tid & 1, side = (tid >> 1) & 1, kgz = (tid >> 2) & 3, r = tid >> 4;
    int chunk = side ? (260 + kgz) : kgz;
    *(int4*)(lds + buf * XS_BUF + r * XS_ROW + chunk * 16) = int4{0, 0, 0, 0};
  }
  // zero y-halo ROWS for edge blocks (never re-staged -> stay zero)
  if (y0 == 0) {
    for (int i = tid; i < 512; i += 512) {
      int buf = i & 1, chunk = 4 + (i >> 1);
      *(int4*)(lds + buf * XS_BUF + chunk * 16) = int4{0, 0, 0, 0};
    }
  }
  if (y0 == 60) {
    for (int i = tid; i < 512; i += 512) {
      int buf = i & 1, chunk = 4 + (i >> 1);
      *(int4*)(lds + buf * XS_BUF + 5 * XS_ROW + chunk * 16) = int4{0, 0, 0, 0};
    }
  }

  // B-fragment read offsets (swizzled): col = ph*32 + (l&31) + dxi,
  // kg = (l>>5) + 2*ks;  addr = (col*4 + (kg ^ ((col>>1)&3))) * 16
  int addrV[2][3][2];
  {
    int lm = l & 31, kh2 = l >> 5;
#pragma unroll
    for (int ph = 0; ph < 2; ++ph)
#pragma unroll
      for (int dxi = 0; dxi < 3; ++dxi)
#pragma unroll
        for (int ks = 0; ks < 2; ++ks) {
          int col = ph * 32 + lm + dxi;                    // 0..65
          int kg  = kh2 + 2 * ks;
          addrV[ph][dxi][ks] = (col * 4 + (kg ^ ((col >> 1) & 3))) * 16;
        }
  }

  // xs staging descriptors: 24 chunks (row r 0..5, quarter q 0..3), wave w
  // takes chunks 3w..3w+2. Packed: r<<28 | dstoff<<13 | srcoff.
  int sdesc[3];
#pragma unroll
  for (int j = 0; j < 3; ++j) {
    int cid = w * 3 + j;
    int r = cid >> 2, q = cid & 3;
    int col_s = 1 + q * 16 + (l >> 2);
    int so = (col_s - 1) * 64 + ((l & 3) ^ ((col_s >> 1) & 3)) * 16;
    int doff = r * XS_ROW + 64 + q * 1024;
    sdesc[j] = (r << 28) | (doff << 13) | so;
  }

  const char* xtb = (const char*)xt;
  // ws DMA source base: per-thread 16B chunk of the block's 16KB kstep slice
  const char* wssrc0 = (const char*)wfrag + (size_t)ocb * 16384 + (size_t)tid * 16;
  // A ds_read base offset within ws buffer: mf_local = wm*2+q -> wm*4096
  int aoff = wm * 4096 + l * 16;

  // prologue: stage xs(g0) (guarded, pre-sync) + ws k0,k1,k2
  {
    size_t gbase = (size_t)(b * 16) * 262144;
#pragma unroll
    for (int j = 0; j < 3; ++j) {
      int d = sdesc[j];
      int so   = d & 8191;
      int doff = (d >> 13) & 32767;
      int r    = d >> 28;
      int gy = y0 - 1 + r;
      if (gy >= 0 && gy < HH)
        gload_lds16(xtb + gbase + (size_t)gy * 4096 + so, lds + doff);
    }
#pragma unroll
    for (int k = 0; k < 3; ++k) {
      const char* s_ = wssrc0 + (size_t)k * 32768;
      char* d_ = wsdst + k * WS_BUFSZ;
      gload_lds16(s_, d_);
      gload_lds16(s_ + 8192, d_ + 8192);
    }
  }
  __syncthreads();

  s16x8 wA[4];
  s16x8 bA[4], bB[4], bC[4];
  AREADB(0)   // kstep 0 (one-time post-sync exposed read)

  for (int g4 = 0; g4 < 3; ++g4) {
    GBODY(0) GBODY(1) GBODY(2) GBODY(3)
  }
  {
    const int g4 = 3;
    GBODY(0) GBODY(1) GBODY(2)
    GBODY_LAST
  }

  // ---- epilogue: demod scale + store ----
  // C/D 32x32: col = l&31, row = (reg&3) + 8*(reg>>2) + 4*(l>>5)
  int gy_base = y0 + wr2;
  int colbase = l & 31;
  int rowadd = 4 * (l >> 5);
#pragma unroll
  for (int q = 0; q < 2; ++q) {
#pragma unroll
    for (int reg = 0; reg < 16; ++reg) {
      int row = (reg & 3) + 8 * (reg >> 2) + rowadd;
      int oc = ocb * 256 + (wm * 2 + q) * 32 + row;
      float dm = demod[b * COUT + oc];
#pragma unroll
      for (int n = 0; n < 4; ++n) {
        int gy = gy_base + (n >> 1);
        int px = (n & 1) * 32 + colbase;
        out[((size_t)(b * COUT + oc)) * 4096 + gy * 64 + px] = acc[q][n][reg] * dm;
      }
    }
  }
}

// ---------------------------------------------------------------------------
extern "C" void kernel_launch(void* const* d_in, const int* in_sizes, int n_in,
                              void* d_out, int out_size, void* d_ws, size_t ws_size,
                              hipStream_t stream) {
  const float* input = (const float*)d_in[0];  // [8,512,64,64]
  const float* style = (const float*)d_in[1];  // [8,512]
  const float* wa    = (const float*)d_in[2];  // [512,512]
  const float* ba    = (const float*)d_in[3];  // [1,512]
  const float* wconv = (const float*)d_in[4];  // [512,512,3,3]
  float* out = (float*)d_out;

  float* smod  = (float*)d_ws;                    // 4096 f
  float* demod = smod + BB * CIN;                 // 4096 f
  float* wsq   = demod + BB * COUT;               // 262144 f
  ushort* wfrag = (ushort*)(wsq + (size_t)COUT * CIN);   // 2,359,296 us (4.5 MB)
  ushort* xt    = wfrag + (size_t)16 * 9 * 32 * 64 * 8;  // 16,777,216 us (32 MB)

  prep1_kernel<<<3200, 256, 0, stream>>>(style, wa, ba, smod, wconv, wsq, wfrag);
  prep2_kernel<<<9216, 256, 0, stream>>>(smod, wsq, demod, input, xt);
  conv_mfma<<<2 * BB * 16, 512, 0, stream>>>(xt, wfrag, demod, out);
}